// Round 8
// baseline (121.139 us; speedup 1.0000x reference)
//
#include <hip/hip_runtime.h>

#define N 8192
#define D 128
#define CHUNK 256
#define NT (CHUNK / 16)        // 16 col-tiles per chunk
#define NCC (N / CHUNK)        // 32 column chunks
#define NBIN 81                // labels -1..79 -> bins 0..80
#define PBLK 512               // prep grid (16 rows/block)

typedef unsigned short u16;
typedef __attribute__((ext_vector_type(8))) __bf16 bf16x8;
typedef __attribute__((ext_vector_type(4))) float f32x4;

// scale = sqrt(10 * log2(e)): dot of two scaled rows = log2(e^{cos/T}),
// so e^{sim} = exp2(acc) with NO per-element multiply.
#define PREP_SCALE 3.7982889979f

__device__ __forceinline__ u16 f2bf(float x) {
  unsigned u = __float_as_uint(x);
  u += 0x7fff + ((u >> 16) & 1);  // RNE
  return (u16)(u >> 16);
}

// ---- kernel 1: parallel counting-sort rank + normalize + bf16 write --------
// Each of 512 blocks independently histograms ALL labels (32 KB, L1-resident)
// + a partial histogram over j < myBase -> exact stable sorted position for
// its 16 rows. No cross-block state, no serial block (R1's 22us lesson).
// Single-bf16 (no lo split): R4-R7 measured absmax 0.0 with this math.
// Block 0 re-zeroes acc3 and publishes nbg (= #background rows).
__global__ __launch_bounds__(256) void cpe_prep(const float* __restrict__ feat,
                                                const int* __restrict__ labels,
                                                u16* __restrict__ fhi,
                                                int* __restrict__ slab,
                                                float* __restrict__ acc3,
                                                int* __restrict__ nbgp) {
  __shared__ int hist[4][NBIN], part[4][NBIN], lbase[NBIN], lpos[16];
  const int tid = threadIdx.x;
  const int w = tid >> 6, l = tid & 63;
  const int bid = blockIdx.x;
  if (tid < NBIN) {
#pragma unroll
    for (int cp = 0; cp < 4; ++cp) { hist[cp][tid] = 0; part[cp][tid] = 0; }
  }
  if (bid == 0 && tid < 4) acc3[tid] = 0.0f;
  __syncthreads();
  const int myBase = bid * 16;  // this block's 16 ORIGINAL rows
  for (int j = tid; j < N; j += 256) {
    const int lab = labels[j] + 1;  // 0..80
    atomicAdd(&hist[w][lab], 1);
    if (j < myBase) atomicAdd(&part[w][lab], 1);
  }
  __syncthreads();
  if (tid < NBIN) {
    hist[0][tid] += hist[1][tid] + hist[2][tid] + hist[3][tid];
    part[0][tid] += part[1][tid] + part[2][tid] + part[3][tid];
  }
  __syncthreads();
  if (tid == 0) {  // exclusive scan of 81 bins — trivial
    int s = 0;
    for (int b = 0; b < NBIN; ++b) { lbase[b] = s; s += hist[0][b]; }
    if (bid == 0) *nbgp = lbase[1];  // count of label -1
  }
  __syncthreads();
  if (tid < 16) {  // stable rank -> unique sorted position per row
    const int L = labels[myBase + tid] + 1;
    int pos = lbase[L] + part[0][L];
    for (int k = 0; k < tid; ++k) pos += (labels[myBase + k] + 1 == L) ? 1 : 0;
    lpos[tid] = pos;
    slab[pos] = L - 1;
  }
  __syncthreads();
#pragma unroll
  for (int rr = 0; rr < 4; ++rr) {  // one wave per row, 4 rows per wave
    const int k = w * 4 + rr;
    const float2 x = *(const float2*)&feat[(myBase + k) * D + l * 2];
    float s = x.x * x.x + x.y * x.y;
#pragma unroll
    for (int sh = 1; sh < 64; sh <<= 1) s += __shfl_xor(s, sh);
    const float inv = PREP_SCALE / fmaxf(sqrtf(s), 1e-12f);
    const int pos = lpos[k];
    *(ushort2*)&fhi[pos * D + l * 2] = make_ushort2(f2bf(x.x * inv), f2bf(x.y * inv));
  }
}

// ---- kernel 2: fused sim + masked online reductions, latency-hidden --------
// Grid (32,32): block = 256 rows x 256-col chunk; wave owns 64 rows.
// vs R7 (41us, MfmaUtil 14%, all-idle = exposed L2 latency):
//  (a) bg col-tiles are a PREFIX of each sorted chunk -> wave-uniform jt_lo
//      replaces the data-dependent `continue`; clean loop pipelines.
//  (b) explicit register prefetch of tile jt+1's B-fragments under tile jt's
//      MFMA+exp2 (~200cyc of work covers ~200cyc L2 latency).
//  (c) 1024 blocks -> 4 blocks/CU (2KB LDS, VGPR~100), 2x the waves of R7.
//  (d) all-bg row-waves skip the whole loop (partials = 0).
// B read direct from L1/L2 (fhi = 2MB, L2-resident; Common-mistake #7).
// loss = log(as/ps); mxe/clips provably inactive (R3+, absmax 0.0).
__global__ __launch_bounds__(256, 2) void cpe_main(
    const u16* __restrict__ fhi, const int* __restrict__ slab,
    const int* __restrict__ nbgp, float2* __restrict__ partials) {
  __shared__ int Lab[CHUNK];   // 1 KB: column labels of this chunk
  __shared__ int LabI[256];    // 1 KB: row labels of this row-band (slow path)
  const int rt = blockIdx.x, cc = blockIdx.y;
  const int tid = threadIdx.x;
  const int w = tid >> 6, l = tid & 63, q = l >> 4, m = l & 15;
  const int r0w = rt * 256 + w * 64;
  const int cbase0 = cc * CHUNK;

  Lab[tid] = slab[cbase0 + tid];
  LabI[tid] = slab[rt * 256 + tid];

  // wave-uniform row-label range (labels sorted ascending)
  const int labi_lo = slab[r0w], labi_hi = slab[r0w + 63];
  const int nbg = *nbgp;

  // A fragments straight from global (L2-resident, once)
  bf16x8 Ah[4][4];
#pragma unroll
  for (int tr = 0; tr < 4; ++tr) {
    const int row = r0w + tr * 16 + m;
#pragma unroll
    for (int ks = 0; ks < 4; ++ks)
      Ah[tr][ks] = *(const bf16x8*)&fhi[row * D + ks * 32 + q * 8];
  }

  float ps[4][4], as_[4][4];
#pragma unroll
  for (int tr = 0; tr < 4; ++tr)
#pragma unroll
    for (int v = 0; v < 4; ++v) { ps[tr][v] = 0.f; as_[tr][v] = 0.f; }

  __syncthreads();  // Lab/LabI ready (the ONLY barrier)

  // bg columns are sorted positions 0..nbg-1 -> all-bg tiles are a prefix.
  const int nb = nbg - cbase0;
  const int jt_lo = (nb < 16) ? 0 : ((nb >> 4) < NT ? (nb >> 4) : NT);

  if (labi_hi >= 0 && jt_lo < NT) {  // skip all-bg row-waves entirely
    // preload tile jt_lo's B fragments
    const u16* bp = &fhi[(size_t)(cbase0 + jt_lo * 16 + m) * D + q * 8];
    bf16x8 b0 = *(const bf16x8*)&bp[0];
    bf16x8 b1 = *(const bf16x8*)&bp[32];
    bf16x8 b2 = *(const bf16x8*)&bp[64];
    bf16x8 b3 = *(const bf16x8*)&bp[96];

    for (int jt = jt_lo; jt < NT; ++jt) {
      const int tb = jt * 16;
      // issue next tile's loads NOW; consumed only after this tile's work
      const int jn = (jt + 1 < NT) ? jt + 1 : jt;  // tail refetch, harmless
      const u16* np = &fhi[(size_t)(cbase0 + jn * 16 + m) * D + q * 8];
      const bf16x8 n0 = *(const bf16x8*)&np[0];
      const bf16x8 n1 = *(const bf16x8*)&np[32];
      const bf16x8 n2 = *(const bf16x8*)&np[64];
      const bf16x8 n3 = *(const bf16x8*)&np[96];

      f32x4 acc[4];
#pragma unroll
      for (int tr = 0; tr < 4; ++tr) acc[tr] = (f32x4){0.f, 0.f, 0.f, 0.f};
#pragma unroll
      for (int tr = 0; tr < 4; ++tr) {
        acc[tr] = __builtin_amdgcn_mfma_f32_16x16x32_bf16(Ah[tr][0], b0, acc[tr], 0, 0, 0);
        acc[tr] = __builtin_amdgcn_mfma_f32_16x16x32_bf16(Ah[tr][1], b1, acc[tr], 0, 0, 0);
        acc[tr] = __builtin_amdgcn_mfma_f32_16x16x32_bf16(Ah[tr][2], b2, acc[tr], 0, 0, 0);
        acc[tr] = __builtin_amdgcn_mfma_f32_16x16x32_bf16(Ah[tr][3], b3, acc[tr], 0, 0, 0);
      }

      const int labj_lo = Lab[tb], labj_hi = Lab[tb + 15];
      const bool slow = (labj_lo < 0) | ((labj_hi >= labi_lo) & (labj_lo <= labi_hi));
      if (!slow) {
        // fast path (~97% of tiles): all-fg, no positives, no self
#pragma unroll
        for (int tr = 0; tr < 4; ++tr)
#pragma unroll
          for (int v = 0; v < 4; ++v)
            as_[tr][v] += __builtin_amdgcn_exp2f(acc[tr][v]);
      } else {
        const int labj = Lab[tb + m];
        const bool fgj = labj >= 0;
        const int jbase = cbase0 + tb;
#pragma unroll
        for (int tr = 0; tr < 4; ++tr) {
          if (jbase == r0w + tr * 16) {  // wave-uniform diagonal-tile branch
#pragma unroll
            for (int v = 0; v < 4; ++v) {
              const float e = __builtin_amdgcn_exp2f(acc[tr][v]);
              const float em = (fgj && (m != q * 4 + v)) ? e : 0.0f;
              as_[tr][v] += em;
              ps[tr][v] += (labj == LabI[w * 64 + tr * 16 + q * 4 + v]) ? em : 0.0f;
            }
          } else {
#pragma unroll
            for (int v = 0; v < 4; ++v) {
              const float e = __builtin_amdgcn_exp2f(acc[tr][v]);
              const float em = fgj ? e : 0.0f;
              as_[tr][v] += em;
              ps[tr][v] += (labj == LabI[w * 64 + tr * 16 + q * 4 + v]) ? em : 0.0f;
            }
          }
        }
      }
      b0 = n0; b1 = n1; b2 = n2; b3 = n3;  // rotate prefetch
    }
  }

  // reduce across the 16 lanes (m) of each quad; plain float2 store per row
#pragma unroll
  for (int tr = 0; tr < 4; ++tr)
#pragma unroll
    for (int v = 0; v < 4; ++v) {
      float vp = ps[tr][v], va = as_[tr][v];
#pragma unroll
      for (int s = 1; s < 16; s <<= 1) {
        vp += __shfl_xor(vp, s);
        va += __shfl_xor(va, s);
      }
      if (m == 0)
        partials[(size_t)cc * N + r0w + tr * 16 + q * 4 + v] = make_float2(vp, va);
    }
}

// ---- kernel 3: combine partials -> per-row loss -> mean (self-finalizing) --
// R0-proven pattern (~4us). Cross-dispatch visibility of partials is free
// (kernel-boundary release/acquire) — no fences needed.
__global__ __launch_bounds__(256) void cpe_rows(const float2* __restrict__ partials,
                                                const int* __restrict__ slab,
                                                float* __restrict__ acc3,
                                                float* __restrict__ out) {
  const int r = blockIdx.x * 256 + threadIdx.x;
  float psr = 0.f, asr = 0.f;
#pragma unroll
  for (int c = 0; c < NCC; ++c) {
    const float2 p = partials[(size_t)c * N + r];
    psr += p.x;
    asr += p.y;
  }
  const bool fg = slab[r] >= 0;
  const bool valid = fg && (psr > 0.f);  // e>0 => (npos>0 <=> ps>0)
  const float loss = fminf(logf(asr / psr), 10.0f);
  float v0 = valid ? loss : 0.f;
  float v1 = valid ? 1.f : 0.f;
  float v2 = fg ? 1.f : 0.f;
#pragma unroll
  for (int s = 1; s < 64; s <<= 1) {
    v0 += __shfl_xor(v0, s);
    v1 += __shfl_xor(v1, s);
    v2 += __shfl_xor(v2, s);
  }
  __shared__ float red[3][4];
  const int w = threadIdx.x >> 6, l = threadIdx.x & 63;
  if (l == 0) { red[0][w] = v0; red[1][w] = v1; red[2][w] = v2; }
  __syncthreads();
  if (threadIdx.x == 0) {
    atomicAdd(&acc3[0], red[0][0] + red[0][1] + red[0][2] + red[0][3]);
    atomicAdd(&acc3[1], red[1][0] + red[1][1] + red[1][2] + red[1][3]);
    atomicAdd(&acc3[2], red[2][0] + red[2][1] + red[2][2] + red[2][3]);
    __threadfence();
    const unsigned old = atomicAdd((unsigned*)&acc3[3], 1u);
    if (old == gridDim.x - 1) {  // last block finalizes (device-scope reads)
      const float ls = atomicAdd(&acc3[0], 0.0f);
      const float nv = atomicAdd(&acc3[1], 0.0f);
      const float nf = atomicAdd(&acc3[2], 0.0f);
      out[0] = (nf >= 2.0f && nv > 0.0f) ? ls / fmaxf(nv, 1.0f) : 0.0f;
    }
  }
}

extern "C" void kernel_launch(void* const* d_in, const int* in_sizes, int n_in,
                              void* d_out, int out_size, void* d_ws, size_t ws_size,
                              hipStream_t stream) {
  const float* feat = (const float*)d_in[0];
  const int* labels = (const int*)d_in[1];
  float* out = (float*)d_out;
  char* ws = (char*)d_ws;
  u16* fhi = (u16*)ws;                                    // 2 MB
  float2* partials = (float2*)(ws + (size_t)N * D * 2);   // 2 MB (32 chunks)
  char* tail = ws + (size_t)N * D * 2 + (size_t)NCC * N * 8;
  int* slab = (int*)tail;                                 // 32 KB
  float* acc3 = (float*)(tail + N * 4);                   // 4 f32
  int* nbgp = (int*)(tail + N * 4 + 64);                  // 1 int

  cpe_prep<<<PBLK, 256, 0, stream>>>(feat, labels, fhi, slab, acc3, nbgp);
  cpe_main<<<dim3(N / 256, NCC), 256, 0, stream>>>(fhi, slab, nbgp, partials);
  cpe_rows<<<N / 256, 256, 0, stream>>>(partials, slab, acc3, out);
}

// Round 9
// 102.398 us; speedup vs baseline: 1.1830x; 1.1830x over previous
//
#include <hip/hip_runtime.h>

#define N 8192
#define D 128
#define CHUNK 512
#define NCC (N / CHUNK)        // 16 column chunks
#define TILE_IT (CHUNK / 128)  // 4 B-tiles per chunk
#define NBIN 81                // labels -1..79 -> bins 0..80
#define PBLK 512               // prep grid (16 rows/block)

typedef unsigned short u16;
typedef __attribute__((ext_vector_type(8))) __bf16 bf16x8;
typedef __attribute__((ext_vector_type(4))) float f32x4;

// scale = sqrt(10 * log2(e)): dot of two scaled rows = log2(e^{cos/T}),
// so e^{sim} = exp2(acc) with NO per-element multiply.
#define PREP_SCALE 3.7982889979f

__device__ __forceinline__ u16 f2bf(float x) {
  unsigned u = __float_as_uint(x);
  u += 0x7fff + ((u >> 16) & 1);  // RNE
  return (u16)(u >> 16);
}

// ---- kernel 1: parallel counting-sort rank + normalize + bf16 write --------
// Each of 512 blocks independently histograms ALL labels (32 KB, L1-resident)
// + a partial histogram over j < myBase -> exact stable sorted position for
// its 16 rows. No cross-block state, no serial block (R1's 22us lesson).
// Single-bf16 (no lo split): R4-R8 measured absmax 0.0 with this math.
// Block 0 re-zeroes acc3 (re-poison safe).
__global__ __launch_bounds__(256) void cpe_prep(const float* __restrict__ feat,
                                                const int* __restrict__ labels,
                                                u16* __restrict__ fhi,
                                                int* __restrict__ slab,
                                                float* __restrict__ acc3) {
  __shared__ int hist[4][NBIN], part[4][NBIN], lbase[NBIN], lpos[16];
  const int tid = threadIdx.x;
  const int w = tid >> 6, l = tid & 63;
  const int bid = blockIdx.x;
  if (tid < NBIN) {
#pragma unroll
    for (int cp = 0; cp < 4; ++cp) { hist[cp][tid] = 0; part[cp][tid] = 0; }
  }
  if (bid == 0 && tid < 4) acc3[tid] = 0.0f;
  __syncthreads();
  const int myBase = bid * 16;  // this block's 16 ORIGINAL rows
  for (int j = tid; j < N; j += 256) {
    const int lab = labels[j] + 1;  // 0..80
    atomicAdd(&hist[w][lab], 1);
    if (j < myBase) atomicAdd(&part[w][lab], 1);
  }
  __syncthreads();
  if (tid < NBIN) {
    hist[0][tid] += hist[1][tid] + hist[2][tid] + hist[3][tid];
    part[0][tid] += part[1][tid] + part[2][tid] + part[3][tid];
  }
  __syncthreads();
  if (tid == 0) {  // exclusive scan of 81 bins — trivial
    int s = 0;
    for (int b = 0; b < NBIN; ++b) { lbase[b] = s; s += hist[0][b]; }
  }
  __syncthreads();
  if (tid < 16) {  // stable rank -> unique sorted position per row
    const int L = labels[myBase + tid] + 1;
    int pos = lbase[L] + part[0][L];
    for (int k = 0; k < tid; ++k) pos += (labels[myBase + k] + 1 == L) ? 1 : 0;
    lpos[tid] = pos;
    slab[pos] = L - 1;
  }
  __syncthreads();
#pragma unroll
  for (int rr = 0; rr < 4; ++rr) {  // one wave per row, 4 rows per wave
    const int k = w * 4 + rr;
    const float2 x = *(const float2*)&feat[(myBase + k) * D + l * 2];
    float s = x.x * x.x + x.y * x.y;
#pragma unroll
    for (int sh = 1; sh < 64; sh <<= 1) s += __shfl_xor(s, sh);
    const float inv = PREP_SCALE / fmaxf(sqrtf(s), 1e-12f);
    const int pos = lpos[k];
    *(ushort2*)&fhi[pos * D + l * 2] = make_ushort2(f2bf(x.x * inv), f2bf(x.y * inv));
  }
}

// ---- kernel 2: fused sim + masked reductions, 2-PHASE double-buffered ------
// R6-proven kernel (LDS staging, CHUNK 512, single-bf16, ~33us) with the T3
// minimum 2-phase pipeline: STAGE(next tile) is issued BEFORE computing the
// current tile, and the single end-of-tile __syncthreads (vmcnt(0) drain)
// lands after ~2us of MFMA+exp2 has covered the load latency. R6's version
// staged AFTER the barrier -> every tile paid the full latency exposed
// (R7/R8 proved reg-prefetch/direct-L2 do NOT fix this; LDS DMA + pipeline
// does). Barriers per block: 8 -> 5, each ~free.
// SORTED label order: ~97% of 16-col tiles take the {exp2, add} fast path;
// all-bg tiles skip MFMA. loss = log(as/ps) (mxe/clips provably inactive).
__global__ __launch_bounds__(256, 2) void cpe_main(
    const u16* __restrict__ fhi, const int* __restrict__ slab,
    float2* __restrict__ partials) {
  __shared__ __align__(16) u16 Bh[2][128 * 128];  // 2 x 32 KB, XOR-swizzled
  __shared__ int Lab[CHUNK];                      // 2 KB
  const int rt = blockIdx.x, cc = blockIdx.y;
  const int tid = threadIdx.x;
  const int w = tid >> 6, l = tid & 63, q = l >> 4, m = l & 15;
  const int r0w = rt * 256 + w * 64;
  const int cbase0 = cc * CHUNK;

  // stage B tile: global->LDS DMA, 16B/lane, swizzle via the GLOBAL addr.
  // LDS chunk p = w*512 + n*64 + lane -> (r = p>>4, c' = p&15=m); c = c'^(r&15).
#define STAGE(buf, itv)                                                        \
  do {                                                                         \
    const int cbase_ = cbase0 + (itv) * 128;                                   \
    _Pragma("unroll") for (int n = 0; n < 8; ++n) {                            \
      const int r_ = w * 32 + n * 4 + q;                                       \
      const int c_ = m ^ (r_ & 15);                                            \
      const u16* gh_ = &fhi[(size_t)(cbase_ + r_) * D + c_ * 8];               \
      __builtin_amdgcn_global_load_lds(                                        \
          (const __attribute__((address_space(1))) unsigned*)gh_,              \
          (__attribute__((address_space(3))) unsigned*)&Bh[buf][(w * 512 + n * 64) * 8], \
          16, 0, 0);                                                           \
    }                                                                          \
  } while (0)

  STAGE(0, 0);  // prologue: tile 0 in flight while Lab/A-frags load

  Lab[tid] = slab[cbase0 + tid];
  Lab[tid + 256] = slab[cbase0 + 256 + tid];

  // wave-uniform row-label range (labels sorted ascending)
  const int labi_lo = slab[r0w], labi_hi = slab[r0w + 63];

  // A fragments + row labels straight from global (L2-resident, once)
  bf16x8 Ah[4][4];
  int labi[4][4];
#pragma unroll
  for (int tr = 0; tr < 4; ++tr) {
    const int row = r0w + tr * 16 + m;
#pragma unroll
    for (int ks = 0; ks < 4; ++ks)
      Ah[tr][ks] = *(const bf16x8*)&fhi[row * D + ks * 32 + q * 8];
#pragma unroll
    for (int v = 0; v < 4; ++v) labi[tr][v] = slab[r0w + tr * 16 + q * 4 + v];
  }

  float ps[4][4], as_[4][4];
#pragma unroll
  for (int tr = 0; tr < 4; ++tr)
#pragma unroll
    for (int v = 0; v < 4; ++v) { ps[tr][v] = 0.f; as_[tr][v] = 0.f; }

  __syncthreads();  // Lab ready + tile 0 staged (vmcnt drained)

  for (int it = 0; it < TILE_IT; ++it) {
    const int cur = it & 1;
    if (it + 1 < TILE_IT) STAGE(cur ^ 1, it + 1);  // overlap: next tile DMA
    const int cbase = cbase0 + it * 128;

    for (int ct = 0; ct < 8; ++ct) {
      const int tb = it * 128 + ct * 16;
      const int labj_lo = Lab[tb], labj_hi = Lab[tb + 15];
      if (labj_hi < 0) continue;  // all-bg tile: every em==0, skip MFMA too
      const bool slow = (labj_lo < 0) | ((labj_hi >= labi_lo) & (labj_lo <= labi_hi));
      const int jj = ct * 16 + m;
      f32x4 acc[4];
#pragma unroll
      for (int tr = 0; tr < 4; ++tr) acc[tr] = (f32x4){0.f, 0.f, 0.f, 0.f};
#pragma unroll
      for (int ks = 0; ks < 4; ++ks) {
        const int off = jj * 128 + ((ks * 4 + q) ^ m) * 8;  // swizzled chunk
        const bf16x8 bh = *(const bf16x8*)&Bh[cur][off];
#pragma unroll
        for (int tr = 0; tr < 4; ++tr)
          acc[tr] = __builtin_amdgcn_mfma_f32_16x16x32_bf16(Ah[tr][ks], bh, acc[tr], 0, 0, 0);
      }
      if (!slow) {
        // fast path (~97% of tiles): all-fg, no positives, no self
#pragma unroll
        for (int tr = 0; tr < 4; ++tr)
#pragma unroll
          for (int v = 0; v < 4; ++v)
            as_[tr][v] += __builtin_amdgcn_exp2f(acc[tr][v]);
      } else {
        const int labj = Lab[tb + m];
        const bool fgj = labj >= 0;
        const int jbase = cbase + ct * 16;
#pragma unroll
        for (int tr = 0; tr < 4; ++tr) {
          if (jbase == r0w + tr * 16) {  // wave-uniform diagonal-tile branch
#pragma unroll
            for (int v = 0; v < 4; ++v) {
              const float e = __builtin_amdgcn_exp2f(acc[tr][v]);
              const float em = (fgj && (m != q * 4 + v)) ? e : 0.0f;
              as_[tr][v] += em;
              ps[tr][v] += (labj == labi[tr][v]) ? em : 0.0f;
            }
          } else {
#pragma unroll
            for (int v = 0; v < 4; ++v) {
              const float e = __builtin_amdgcn_exp2f(acc[tr][v]);
              const float em = fgj ? e : 0.0f;
              as_[tr][v] += em;
              ps[tr][v] += (labj == labi[tr][v]) ? em : 0.0f;
            }
          }
        }
      }
    }
    // single barrier per tile: waves done reading Bh[cur] (so it+1 may
    // overwrite it) AND next tile's DMA drained (vmcnt(0) in syncthreads) —
    // by now its latency was hidden under this tile's MFMA+exp2.
    __syncthreads();
  }
#undef STAGE

  // reduce across the 16 lanes (m) of each quad; plain float2 store per row
#pragma unroll
  for (int tr = 0; tr < 4; ++tr)
#pragma unroll
    for (int v = 0; v < 4; ++v) {
      float vp = ps[tr][v], va = as_[tr][v];
#pragma unroll
      for (int s = 1; s < 16; s <<= 1) {
        vp += __shfl_xor(vp, s);
        va += __shfl_xor(va, s);
      }
      if (m == 0)
        partials[(size_t)cc * N + r0w + tr * 16 + q * 4 + v] = make_float2(vp, va);
    }
}

// ---- kernel 3: combine partials -> per-row loss -> mean (self-finalizing) --
// R0-proven pattern (~4us). Cross-dispatch visibility of partials is free
// (kernel-boundary release/acquire) — no fences needed.
__global__ __launch_bounds__(256) void cpe_rows(const float2* __restrict__ partials,
                                                const int* __restrict__ slab,
                                                float* __restrict__ acc3,
                                                float* __restrict__ out) {
  const int r = blockIdx.x * 256 + threadIdx.x;
  float psr = 0.f, asr = 0.f;
#pragma unroll
  for (int c = 0; c < NCC; ++c) {
    const float2 p = partials[(size_t)c * N + r];
    psr += p.x;
    asr += p.y;
  }
  const bool fg = slab[r] >= 0;
  const bool valid = fg && (psr > 0.f);  // e>0 => (npos>0 <=> ps>0)
  const float loss = fminf(logf(asr / psr), 10.0f);
  float v0 = valid ? loss : 0.f;
  float v1 = valid ? 1.f : 0.f;
  float v2 = fg ? 1.f : 0.f;
#pragma unroll
  for (int s = 1; s < 64; s <<= 1) {
    v0 += __shfl_xor(v0, s);
    v1 += __shfl_xor(v1, s);
    v2 += __shfl_xor(v2, s);
  }
  __shared__ float red[3][4];
  const int w = threadIdx.x >> 6, l = threadIdx.x & 63;
  if (l == 0) { red[0][w] = v0; red[1][w] = v1; red[2][w] = v2; }
  __syncthreads();
  if (threadIdx.x == 0) {
    atomicAdd(&acc3[0], red[0][0] + red[0][1] + red[0][2] + red[0][3]);
    atomicAdd(&acc3[1], red[1][0] + red[1][1] + red[1][2] + red[1][3]);
    atomicAdd(&acc3[2], red[2][0] + red[2][1] + red[2][2] + red[2][3]);
    __threadfence();
    const unsigned old = atomicAdd((unsigned*)&acc3[3], 1u);
    if (old == gridDim.x - 1) {  // last block finalizes (device-scope reads)
      const float ls = atomicAdd(&acc3[0], 0.0f);
      const float nv = atomicAdd(&acc3[1], 0.0f);
      const float nf = atomicAdd(&acc3[2], 0.0f);
      out[0] = (nf >= 2.0f && nv > 0.0f) ? ls / fmaxf(nv, 1.0f) : 0.0f;
    }
  }
}

extern "C" void kernel_launch(void* const* d_in, const int* in_sizes, int n_in,
                              void* d_out, int out_size, void* d_ws, size_t ws_size,
                              hipStream_t stream) {
  const float* feat = (const float*)d_in[0];
  const int* labels = (const int*)d_in[1];
  float* out = (float*)d_out;
  char* ws = (char*)d_ws;
  u16* fhi = (u16*)ws;                                    // 2 MB
  float2* partials = (float2*)(ws + (size_t)N * D * 2);   // 1 MB (16 chunks)
  char* tail = ws + (size_t)N * D * 2 + (size_t)NCC * N * 8;
  int* slab = (int*)tail;                                 // 32 KB
  float* acc3 = (float*)(tail + N * 4);                   // 4 f32

  cpe_prep<<<PBLK, 256, 0, stream>>>(feat, labels, fhi, slab, acc3);
  cpe_main<<<dim3(N / 256, NCC), 256, 0, stream>>>(fhi, slab, partials);
  cpe_rows<<<N / 256, 256, 0, stream>>>(partials, slab, acc3, out);
}